// Round 3
// baseline (773.522 us; speedup 1.0000x reference)
//
#include <hip/hip_runtime.h>

#define Bdim 8
#define Ddim 64
#define Hdim 384
#define Wdim 512

// Output tile: 16 rows x 64 cols per block; 256 threads, each owns 4 pixels
// (wave wv covers rows ty+4*wv .. ty+4*wv+3, full 64-wide row per lane-row).
#define TH 16
#define TW 64
#define TILES_W (Wdim / TW)               // 8
#define TILES_H (Hdim / TH)               // 24
#define TILES_PER_B (TILES_W * TILES_H)   // 192

// Staged LDS window per d-slice: 32 rows x 96 cols (+-8 row / +-16 col halo,
// clamped inside the image). Row stride 104 floats => 8-bank skew per row.
#define YH 32
#define XW 96
#define LSTRIDE 104

// tile col in LOW 3 bits of blockIdx: vertical neighbors differ by 8 -> same
// XCD under round-robin -> 16-row window overlap is an L2 hit (kept from R1).

__global__ __launch_bounds__(256, 4) void resample2d_kernel(
    const float* __restrict__ img,   // (B, D, H, W)
    const float* __restrict__ flow,  // (B, 2, H, W)
    float* __restrict__ out)         // (B, D, H, W)
{
    __shared__ float S[YH * LSTRIDE];

    const int HW = Hdim * Wdim;
    int bid = blockIdx.x;
    int b   = bid / TILES_PER_B;
    int s   = bid - b * TILES_PER_B;
    int tr  = s >> 3;                 // tile row 0..23
    int tc  = s & 7;                  // tile col 0..7 -> XCD id
    int ty  = tr * TH, tx = tc * TW;

    int lane = threadIdx.x & 63;
    int wv   = threadIdx.x >> 6;
    int w    = tx + lane;

    int YLO = max(0, min(ty - 8,  Hdim - YH));   // multiple of 8
    int XLO = max(0, min(tx - 16, Wdim - XW));   // multiple of 16 -> float4 aligned

    const float* fb = flow + (size_t)b * 2 * HW;
    const float* ib = img  + (size_t)b * Ddim * HW;
    float*       ob = out  + (size_t)b * Ddim * HW;

    // ---- per-pixel setup (d-invariant): weights, LDS addr, fallback addr ----
    float w00[4], w01[4], w10[4], w11[4];
    int   lA[4], gA[4], oA[4];
    bool  ok[4];

    #pragma unroll
    for (int r = 0; r < 4; ++r) {
        int h  = ty + wv * 4 + r;
        int hw = h * Wdim + w;
        float u = __builtin_nontemporal_load(fb + hw);
        float v = __builtin_nontemporal_load(fb + HW + hw);

        float fx = fminf(fmaxf((float)w + u, 0.0f), (float)(Wdim - 1));
        float fy = fminf(fmaxf((float)h + v, 0.0f), (float)(Hdim - 1));
        // clamp folded into weight: pair (x0,x0+1) always in-bounds & contiguous
        int x0 = min((int)floorf(fx), Wdim - 2);
        int y0 = min((int)floorf(fy), Hdim - 2);
        float wx = fx - (float)x0;
        float wy = fy - (float)y0;

        w00[r] = (1.0f - wy) * (1.0f - wx);
        w01[r] = (1.0f - wy) * wx;
        w10[r] = wy * (1.0f - wx);
        w11[r] = wy * wx;

        gA[r] = y0 * Wdim + x0;                        // global fallback (elems)
        lA[r] = (y0 - YLO) * LSTRIDE + (x0 - XLO);     // LDS f32 index
        oA[r] = hw;
        // window must contain (y0..y0+1, x0..x0+1)
        ok[r] = (x0 >= XLO) & (x0 <= XLO + XW - 2) &
                (y0 >= YLO) & (y0 <= YLO + YH - 2);
    }

    // ---- staging geometry (d-invariant): 32x96 floats = 768 float4, 3/thread ----
    int goff[3], loff[3];
    #pragma unroll
    for (int k = 0; k < 3; ++k) {
        int i   = (int)threadIdx.x + 256 * k;  // 0..767
        int row = i / 24;                      // 0..31
        int c   = i - row * 24;                // 0..23
        goff[k] = (YLO + row) * Wdim + XLO + 4 * c;
        loff[k] = row * LSTRIDE + 4 * c;       // multiple of 4 -> 16B aligned
    }

    auto LOADS = [&](int d, float4& s0, float4& s1, float4& s2) {
        const float* p = ib + (size_t)d * HW;
        s0 = *(const float4*)(p + goff[0]);
        s1 = *(const float4*)(p + goff[1]);
        s2 = *(const float4*)(p + goff[2]);
    };
    auto WRITE = [&](const float4& s0, const float4& s1, const float4& s2) {
        *(float4*)(&S[loff[0]]) = s0;
        *(float4*)(&S[loff[1]]) = s1;
        *(float4*)(&S[loff[2]]) = s2;
    };
    auto COMPUTE = [&](int d) {
        const float* p = ib + (size_t)d * HW;
        float*       o = ob + (size_t)d * HW;
        #pragma unroll
        for (int r = 0; r < 4; ++r) {
            float f00, f01, f10, f11;
            if (__builtin_expect((int)ok[r], 1)) {
                int a = lA[r];
                f00 = S[a];            f01 = S[a + 1];             // ds_read2_b32
                f10 = S[a + LSTRIDE];  f11 = S[a + LSTRIDE + 1];   // ds_read2_b32
            } else {           // pathological flow only: exact global fallback
                const float* q = p + gA[r];
                float2 lo = *(const float2*)q;
                float2 hi = *(const float2*)(q + Wdim);
                f00 = lo.x; f01 = lo.y; f10 = hi.x; f11 = hi.y;
            }
            float res = f00 * w00[r] + f01 * w01[r]
                      + f10 * w10[r] + f11 * w11[r];
            __builtin_nontemporal_store(res, o + oA[r]);
        }
    };

    // ---- software-pipelined d-loop: prefetch d+1 while computing d ----
    float4 a0, a1, a2, b0, b1, b2;
    LOADS(0, a0, a1, a2);
    for (int d = 0; d < Ddim; d += 2) {
        __syncthreads();               // prior COMPUTE's LDS reads done
        WRITE(a0, a1, a2);
        LOADS(d + 1, b0, b1, b2);      // in flight during COMPUTE(d)
        __syncthreads();
        COMPUTE(d);

        __syncthreads();
        WRITE(b0, b1, b2);
        if (d + 2 < Ddim) LOADS(d + 2, a0, a1, a2);
        __syncthreads();
        COMPUTE(d + 1);
    }
}

extern "C" void kernel_launch(void* const* d_in, const int* in_sizes, int n_in,
                              void* d_out, int out_size, void* d_ws, size_t ws_size,
                              hipStream_t stream) {
    const float* img  = (const float*)d_in[0];
    const float* flow = (const float*)d_in[1];
    float* out = (float*)d_out;

    const int total_blocks = Bdim * TILES_PER_B;  // 1536
    dim3 block(256);
    dim3 grid(total_blocks);
    resample2d_kernel<<<grid, block, 0, stream>>>(img, flow, out);
}

// Round 4
// 760.748 us; speedup vs baseline: 1.0168x; 1.0168x over previous
//
#include <hip/hip_runtime.h>

#define Bdim 8
#define Ddim 64
#define Hdim 384
#define Wdim 512

// Output tile: 16 rows x 64 cols per block; 256 threads, each owns 4 pixels.
// Each block handles a 16-deep d-chunk -> grid = 8*24*4*8 = 6144 blocks.
#define TH 16
#define TW 64
#define TILES_W (Wdim / TW)               // 8
#define TILES_H (Hdim / TH)               // 24
#define DBLK 16
#define DCHUNKS (Ddim / DBLK)             // 4

// Staged LDS window per d-slice: 32 rows x 96 cols (+-8 row / +-16 col halo,
// clamped inside the image). Row stride 104 floats (8-bank skew per row).
// DOUBLE buffered: 2 x 13312 B = 26624 B -> 6 blocks/CU -> 24 waves (75%).
#define YH 32
#define XW 96
#define LSTRIDE 104
#define LDS_FLOATS (YH * LSTRIDE)

// blockIdx layout: (((b*TILES_H + tr)*DCHUNKS + dc)*TILES_W) + tc
// -> tc in LOW 3 bits (XCD id under round-robin); vertical neighbor tiles
// differ by 32 -> same XCD -> 16-row window overlap is an L2 hit.

__global__ __launch_bounds__(256, 6) void resample2d_kernel(
    const float* __restrict__ img,   // (B, D, H, W)
    const float* __restrict__ flow,  // (B, 2, H, W)
    float* __restrict__ out)         // (B, D, H, W)
{
    __shared__ float SA[LDS_FLOATS];
    __shared__ float SB[LDS_FLOATS];

    const int HW = Hdim * Wdim;
    int bid = blockIdx.x;
    int tc  = bid & 7;
    int t1  = bid >> 3;
    int dc  = t1 & 3;
    int t2  = t1 >> 2;
    int tr  = t2 % TILES_H;
    int b   = t2 / TILES_H;
    int ty  = tr * TH, tx = tc * TW;
    int d0  = dc * DBLK;

    int lane = threadIdx.x & 63;
    int wv   = threadIdx.x >> 6;
    int w    = tx + lane;

    int YLO = max(0, min(ty - 8,  Hdim - YH));
    int XLO = max(0, min(tx - 16, Wdim - XW));   // multiple of 16 -> 64B aligned

    const float* fb = flow + (size_t)b * 2 * HW;
    const float* ib = img  + (size_t)b * Ddim * HW;
    float*       ob = out  + (size_t)b * Ddim * HW;

    // ---- per-pixel setup (d-invariant): weights, LDS addr, fallback addr ----
    float w00[4], w01[4], w10[4], w11[4];
    int   lA[4], gA[4], oA[4];
    bool  ok[4];

    #pragma unroll
    for (int r = 0; r < 4; ++r) {
        int h  = ty + wv * 4 + r;
        int hw = h * Wdim + w;
        float u = __builtin_nontemporal_load(fb + hw);
        float v = __builtin_nontemporal_load(fb + HW + hw);

        float fx = fminf(fmaxf((float)w + u, 0.0f), (float)(Wdim - 1));
        float fy = fminf(fmaxf((float)h + v, 0.0f), (float)(Hdim - 1));
        // clamp folded into weight: pair (x0,x0+1) always in-bounds & contiguous
        int x0 = min((int)floorf(fx), Wdim - 2);
        int y0 = min((int)floorf(fy), Hdim - 2);
        float wx = fx - (float)x0;
        float wy = fy - (float)y0;

        w00[r] = (1.0f - wy) * (1.0f - wx);
        w01[r] = (1.0f - wy) * wx;
        w10[r] = wy * (1.0f - wx);
        w11[r] = wy * wx;

        gA[r] = y0 * Wdim + x0;                        // global fallback (elems)
        lA[r] = (y0 - YLO) * LSTRIDE + (x0 - XLO);     // LDS f32 index
        oA[r] = hw;
        ok[r] = (x0 >= XLO) & (x0 <= XLO + XW - 2) &
                (y0 >= YLO) & (y0 <= YLO + YH - 2);
    }

    // ---- staging geometry (d-invariant): 32x96 floats = 768 float4, 3/thread ----
    int goff[3], loff[3];
    #pragma unroll
    for (int k = 0; k < 3; ++k) {
        int i   = (int)threadIdx.x + 256 * k;  // 0..767
        int row = i / 24;                      // 0..31
        int c   = i - row * 24;                // 0..23
        goff[k] = (YLO + row) * Wdim + XLO + 4 * c;
        loff[k] = row * LSTRIDE + 4 * c;       // 16B aligned
    }

    auto LOADS = [&](int d, float4& s0, float4& s1, float4& s2) {
        const float* p = ib + (size_t)d * HW;
        s0 = *(const float4*)(p + goff[0]);
        s1 = *(const float4*)(p + goff[1]);
        s2 = *(const float4*)(p + goff[2]);
    };
    auto WRITE = [&](float* S, const float4& s0, const float4& s1, const float4& s2) {
        *(float4*)(S + loff[0]) = s0;
        *(float4*)(S + loff[1]) = s1;
        *(float4*)(S + loff[2]) = s2;
    };
    auto COMPUTE = [&](int d, const float* S) {
        const float* p = ib + (size_t)d * HW;
        float*       o = ob + (size_t)d * HW;
        #pragma unroll
        for (int r = 0; r < 4; ++r) {
            float f00, f01, f10, f11;
            if (__builtin_expect((int)ok[r], 1)) {
                int a = lA[r];
                f00 = S[a];            f01 = S[a + 1];             // ds_read2_b32
                f10 = S[a + LSTRIDE];  f11 = S[a + LSTRIDE + 1];   // ds_read2_b32
            } else {           // pathological flow only: exact global fallback
                const float* q = p + gA[r];
                float2 lo = *(const float2*)q;
                float2 hi = *(const float2*)(q + Wdim);
                f00 = lo.x; f01 = lo.y; f10 = hi.x; f11 = hi.y;
            }
            float res = f00 * w00[r] + f01 * w01[r]
                      + f10 * w10[r] + f11 * w11[r];
            __builtin_nontemporal_store(res, o + oA[r]);
        }
    };

    // ---- double-buffered d-loop: ONE barrier per d-slice ----
    // iter even: compute SA, write SB (from rB), prefetch d+2 -> rA
    // iter odd : compute SB, write SA (from rA), prefetch d+3 -> rB
    float4 a0, a1, a2, b0, b1, b2;
    LOADS(d0, a0, a1, a2);
    WRITE(SA, a0, a1, a2);
    LOADS(d0 + 1, b0, b1, b2);
    __syncthreads();

    #pragma unroll
    for (int dd = 0; dd < DBLK; dd += 2) {
        WRITE(SB, b0, b1, b2);                       // SB readers done (prev barrier)
        if (dd + 2 < DBLK) LOADS(d0 + dd + 2, a0, a1, a2);
        COMPUTE(d0 + dd, SA);
        __syncthreads();

        if (dd + 2 < DBLK) WRITE(SA, a0, a1, a2);    // SA readers done (prev barrier)
        if (dd + 3 < DBLK) LOADS(d0 + dd + 3, b0, b1, b2);
        COMPUTE(d0 + dd + 1, SB);
        __syncthreads();
    }
}

extern "C" void kernel_launch(void* const* d_in, const int* in_sizes, int n_in,
                              void* d_out, int out_size, void* d_ws, size_t ws_size,
                              hipStream_t stream) {
    const float* img  = (const float*)d_in[0];
    const float* flow = (const float*)d_in[1];
    float* out = (float*)d_out;

    const int total_blocks = Bdim * TILES_H * DCHUNKS * TILES_W;  // 6144
    dim3 block(256);
    dim3 grid(total_blocks);
    resample2d_kernel<<<grid, block, 0, stream>>>(img, flow, out);
}

// Round 5
// 735.311 us; speedup vs baseline: 1.0520x; 1.0346x over previous
//
#include <hip/hip_runtime.h>

#define Bdim 8
#define Ddim 64
#define Hdim 384
#define Wdim 512

// Output tile: 16 rows x 64 cols per block; 256 threads.
// Each thread owns a 1x4 HORIZONTAL strip -> float4 stores (1KB/wave-instr,
// the granularity at which m13's copy hits 6.3 TB/s) and float4 flow loads.
// Wave = 4 rows x 16 lane-groups.
#define TH 16
#define TW 64
#define TILES_W (Wdim / TW)               // 8
#define TILES_H (Hdim / TH)               // 24
#define DBLK 16
#define DCHUNKS (Ddim / DBLK)             // 4

// Staged LDS window per d-slice: 32 rows x 96 cols (+-8 row / +-16 col halo,
// clamped inside the image). Row stride 104 floats (8-bank skew per row).
// Double buffered: 2 x 13312 B = 26624 B -> 6 blocks/CU -> 24 waves (75%).
#define YH 32
#define XW 96
#define LSTRIDE 104
#define LDS_FLOATS (YH * LSTRIDE)

// blockIdx layout: (((b*TILES_H + tr)*DCHUNKS + dc)*TILES_W) + tc
// -> tc in LOW 3 bits (XCD id under round-robin); vertically/depth adjacent
// tiles land on the same XCD -> shared window rows are L2 hits.

__global__ __launch_bounds__(256, 6) void resample2d_kernel(
    const float* __restrict__ img,   // (B, D, H, W)
    const float* __restrict__ flow,  // (B, 2, H, W)
    float* __restrict__ out)         // (B, D, H, W)
{
    __shared__ float SA[LDS_FLOATS];
    __shared__ float SB[LDS_FLOATS];

    const int HW = Hdim * Wdim;
    int bid = blockIdx.x;
    int tc  = bid & 7;
    int t1  = bid >> 3;
    int dc  = t1 & 3;
    int t2  = t1 >> 2;
    int tr  = t2 % TILES_H;
    int b   = t2 / TILES_H;
    int ty  = tr * TH, tx = tc * TW;
    int d0  = dc * DBLK;

    int lane = threadIdx.x & 63;
    int wv   = threadIdx.x >> 6;
    int h    = ty + wv * 4 + (lane >> 4);       // 4 rows per wave
    int w0   = tx + (lane & 15) * 4;            // 4-px horizontal strip

    int YLO = max(0, min(ty - 8,  Hdim - YH));
    int XLO = max(0, min(tx - 16, Wdim - XW));  // multiple of 16 -> 64B aligned

    const float* fb = flow + (size_t)b * 2 * HW;
    const float* ib = img  + (size_t)b * Ddim * HW;
    float*       ob = out  + (size_t)b * Ddim * HW;

    // ---- per-pixel setup (d-invariant): weights, LDS addr, fallback addr ----
    int hw0 = h * Wdim + w0;
    float4 u4 = *(const float4*)(fb + hw0);        // plain loads: L3 keeps flow
    float4 v4 = *(const float4*)(fb + HW + hw0);   // for the other 3 d-chunks

    float w00[4], w01[4], w10[4], w11[4];
    int   lA[4], yx[4];
    bool  ok[4];
    {
        const float uu[4] = {u4.x, u4.y, u4.z, u4.w};
        const float vv[4] = {v4.x, v4.y, v4.z, v4.w};
        #pragma unroll
        for (int j = 0; j < 4; ++j) {
            int w = w0 + j;
            float fx = fminf(fmaxf((float)w + uu[j], 0.0f), (float)(Wdim - 1));
            float fy = fminf(fmaxf((float)h + vv[j], 0.0f), (float)(Hdim - 1));
            // clamp folded into weight: pair (x0,x0+1) always in-bounds, contiguous
            int x0 = min((int)floorf(fx), Wdim - 2);
            int y0 = min((int)floorf(fy), Hdim - 2);
            float wx = fx - (float)x0;
            float wy = fy - (float)y0;
            w00[j] = (1.0f - wy) * (1.0f - wx);
            w01[j] = (1.0f - wy) * wx;
            w10[j] = wy * (1.0f - wx);
            w11[j] = wy * wx;
            lA[j] = (y0 - YLO) * LSTRIDE + (x0 - XLO);
            yx[j] = (y0 << 16) | x0;               // packed for the cold fallback
            ok[j] = (x0 >= XLO) & (x0 <= XLO + XW - 2) &
                    (y0 >= YLO) & (y0 <= YLO + YH - 2);
        }
    }

    // ---- staging geometry (d-invariant): 32x96 floats = 768 float4, 3/thread ----
    int goff[3], loff[3];
    #pragma unroll
    for (int k = 0; k < 3; ++k) {
        int i   = (int)threadIdx.x + 256 * k;  // 0..767
        int row = i / 24;                      // 0..31
        int c   = i - row * 24;                // 0..23
        goff[k] = (YLO + row) * Wdim + XLO + 4 * c;
        loff[k] = row * LSTRIDE + 4 * c;       // 16B aligned
    }

    auto LOADS = [&](int d, float4& s0, float4& s1, float4& s2) {
        const float* p = ib + (size_t)d * HW;
        s0 = *(const float4*)(p + goff[0]);
        s1 = *(const float4*)(p + goff[1]);
        s2 = *(const float4*)(p + goff[2]);
    };
    auto WRITE = [&](float* S, const float4& s0, const float4& s1, const float4& s2) {
        *(float4*)(S + loff[0]) = s0;
        *(float4*)(S + loff[1]) = s1;
        *(float4*)(S + loff[2]) = s2;
    };
    auto COMPUTE = [&](int d, const float* S) {
        const float* p = ib + (size_t)d * HW;
        float res[4];
        #pragma unroll
        for (int j = 0; j < 4; ++j) {
            float f00, f01, f10, f11;
            if (__builtin_expect((int)ok[j], 1)) {
                int a = lA[j];
                f00 = S[a];            f01 = S[a + 1];             // ds_read2_b32
                f10 = S[a + LSTRIDE];  f11 = S[a + LSTRIDE + 1];   // ds_read2_b32
            } else {           // pathological flow only: exact global fallback
                const float* q = p + (yx[j] >> 16) * Wdim + (yx[j] & 0xffff);
                float2 lo = *(const float2*)q;
                float2 hi = *(const float2*)(q + Wdim);
                f00 = lo.x; f01 = lo.y; f10 = hi.x; f11 = hi.y;
            }
            res[j] = f00 * w00[j] + f01 * w01[j]
                   + f10 * w10[j] + f11 * w11[j];
        }
        // plain (cached) float4 store: 1KB per wave-instr, L2 write-coalesced
        *(float4*)(ob + (size_t)d * HW + hw0) =
            make_float4(res[0], res[1], res[2], res[3]);
    };

    // ---- double-buffered d-loop: ONE barrier per d-slice ----
    float4 a0, a1, a2, b0, b1, b2;
    LOADS(d0, a0, a1, a2);
    WRITE(SA, a0, a1, a2);
    LOADS(d0 + 1, b0, b1, b2);
    __syncthreads();

    #pragma unroll
    for (int dd = 0; dd < DBLK; dd += 2) {
        WRITE(SB, b0, b1, b2);                       // SB readers done (prev barrier)
        if (dd + 2 < DBLK) LOADS(d0 + dd + 2, a0, a1, a2);
        COMPUTE(d0 + dd, SA);
        __syncthreads();

        if (dd + 2 < DBLK) WRITE(SA, a0, a1, a2);    // SA readers done (prev barrier)
        if (dd + 3 < DBLK) LOADS(d0 + dd + 3, b0, b1, b2);
        COMPUTE(d0 + dd + 1, SB);
        __syncthreads();
    }
}

extern "C" void kernel_launch(void* const* d_in, const int* in_sizes, int n_in,
                              void* d_out, int out_size, void* d_ws, size_t ws_size,
                              hipStream_t stream) {
    const float* img  = (const float*)d_in[0];
    const float* flow = (const float*)d_in[1];
    float* out = (float*)d_out;

    const int total_blocks = Bdim * TILES_H * DCHUNKS * TILES_W;  // 6144
    dim3 block(256);
    dim3 grid(total_blocks);
    resample2d_kernel<<<grid, block, 0, stream>>>(img, flow, out);
}